// Round 13
// baseline (779.335 us; speedup 1.0000x reference)
//
#include <hip/hip_runtime.h>
#include <hip/hip_bf16.h>
#include <math.h>

typedef __attribute__((ext_vector_type(8))) short bf16x8;
typedef __attribute__((ext_vector_type(4))) float f32x4;

#define NB 2048
#define NT 64
#define ND 512
#define NS 64
#define NTH 512
#define LN_EPS 1e-5f

// ---- LDS layout (bytes) ----
#define XH_B    0        // bf16 [64][512] swizzled (65536)
#define HS_B    65536    // bf16 [64][64] swizzled (8192)
#define SCANF_B 73728    // f32 [64]
#define HT_B    73984    // f32 [64]
#define STM_B   74240    // f32 [512]
#define RED_B   76288    // f32 [32]
#define LDS_BYTES 76416  // x2 = 152832 <= 160KiB -> 2 blocks/CU

// ws (ushort): BdPack [2][4][16][64][8] @0 ; BbPack @65536 ; WcPack [2][32][2][64][8] @131072 ;
//              WsP [2][64][512] @196608 ; posP [64][512] @262144
#define BB_OFF  65536
#define BC_OFF  131072
#define WS_OFF  196608
#define POS_OFF 262144
#define PACK_ELEMS 294912

__device__ __forceinline__ unsigned short f2b(float x) {
    __hip_bfloat16 h = __float2bfloat16(x);
    return *(unsigned short*)&h;
}
__device__ __forceinline__ float b2f(unsigned short u) {
    __hip_bfloat16 h; *(unsigned short*)&h = u;
    return __bfloat162float(h);
}
__device__ __forceinline__ int xh_off(int t, int cb) { return t * 1024 + (cb ^ ((t & 15) << 4)); }
__device__ __forceinline__ int hs_off(int t, int cb) { return t * 128  + (cb ^ ((t & 7)  << 4)); }

// ---------------- prep: pack weights + pos_emb to bf16 ----------------
__global__ void prep_pack(const float* __restrict__ Wd, const float* __restrict__ Wb,
                          const float* __restrict__ Wc, const float* __restrict__ Ws,
                          const float* __restrict__ pos_emb,
                          unsigned short* __restrict__ pack) {
    int i = blockIdx.x * 256 + threadIdx.x;
    if (i >= PACK_ELEMS) return;
    float v;
    if (i >= POS_OFF) {
        v = pos_emb[i - POS_OFF];
    } else {
        int which = i >> 16;          // 0=Bd 1=Bb 2=Wc 3=Ws
        int r = i & 0xFFFF;
        if (which < 2) {
            int j = r & 7, l = (r >> 3) & 63, ks = (r >> 9) & 15, nt = (r >> 13) & 3, dep = r >> 15;
            int s = nt * 16 + (l & 15);
            int k = ks * 32 + (l >> 4) * 8 + j;
            const float* W = which ? Wb : Wd;
            v = W[(dep * 512 + k) * 64 + s];
        } else if (which == 2) {
            int j = r & 7, l = (r >> 3) & 63, ks = (r >> 9) & 1, ntg = (r >> 10) & 31, dep = r >> 15;
            int d = ntg * 16 + (l & 15);
            int k = ks * 32 + (l >> 4) * 8 + j;
            v = Wc[(dep * 64 + k) * 512 + d];
        } else {
            int dep = r >> 15, rem = r & 0x7FFF;
            v = Ws[dep * (NS * ND) + rem];
        }
    }
    pack[i] = f2b(v);
}

// ---------------- main fused kernel: 1 block per batch element ----------------
__global__ __launch_bounds__(NTH, 4)
void ssm_mfma(const float* __restrict__ tokens,
              const float* __restrict__ A_log,
              const float* __restrict__ bd, const float* __restrict__ bb,
              const float* __restrict__ bc, const float* __restrict__ Dp,
              const float* __restrict__ bs,
              const float* __restrict__ gma, const float* __restrict__ bta,
              const unsigned short* __restrict__ pack,
              float* __restrict__ out_hidden, float* __restrict__ out_shot)
{
    extern __shared__ char sm[];
    float* scanF = (float*)(sm + SCANF_B);
    float* hT    = (float*)(sm + HT_B);
    float* stm   = (float*)(sm + STM_B);
    float* red   = (float*)(sm + RED_B);

    const int tid  = threadIdx.x;
    const int b    = blockIdx.x;
    const int lane = tid & 63;
    const int w    = tid >> 6;
    const int lr   = lane & 15;
    const int lg   = lane >> 4;
    const int nt   = w & 3;
    const int mh   = w >> 2;

    // ---- stage tokens + bf16 pos_emb -> bf16 swizzled xh ----
    {
        const f32x4*   tp = (const f32x4*)(tokens + (size_t)b * (NT * ND));
        const ushort4* pp = (const ushort4*)(pack + POS_OFF);
        #pragma unroll
        for (int i = 0; i < 16; ++i) {
            int f = i * NTH + tid;
            f32x4 a = __builtin_nontemporal_load(&tp[f]);
            ushort4 p = pp[f];
            int row = f >> 7, cb = (f & 127) * 8;
            ushort4 q;
            q.x = f2b(a.x + b2f(p.x));
            q.y = f2b(a.y + b2f(p.y));
            q.z = f2b(a.z + b2f(p.z));
            q.w = f2b(a.w + b2f(p.w));
            *(ushort4*)(sm + XH_B + xh_off(row, cb)) = q;
        }
    }
    __syncthreads();

    for (int dep = 0; dep < 2; ++dep) {
        // ================= phase A: delta_pre / drive_pre via MFMA =================
        f32x4 accD[2] = {f32x4{0,0,0,0}, f32x4{0,0,0,0}};
        f32x4 accB[2] = {f32x4{0,0,0,0}, f32x4{0,0,0,0}};
        {
            const unsigned short* BdP = pack + (dep * 4 + nt) * 8192;
            const unsigned short* BbP = BdP + BB_OFF;
            const int rowA0 = 32 * mh + lr;
            const int rowA1 = rowA0 + 16;
            #pragma unroll 4
            for (int ks = 0; ks < 16; ++ks) {
                int cb = ks * 64 + lg * 16;
                bf16x8 a0 = *(const bf16x8*)(sm + XH_B + xh_off(rowA0, cb));
                bf16x8 a1 = *(const bf16x8*)(sm + XH_B + xh_off(rowA1, cb));
                bf16x8 b0 = *(const bf16x8*)(BdP + ks * 512 + lane * 8);
                bf16x8 b1 = *(const bf16x8*)(BbP + ks * 512 + lane * 8);
                accD[0] = __builtin_amdgcn_mfma_f32_16x16x32_bf16(a0, b0, accD[0], 0, 0, 0);
                accD[1] = __builtin_amdgcn_mfma_f32_16x16x32_bf16(a1, b0, accD[1], 0, 0, 0);
                accB[0] = __builtin_amdgcn_mfma_f32_16x16x32_bf16(a0, b1, accB[0], 0, 0, 0);
                accB[1] = __builtin_amdgcn_mfma_f32_16x16x32_bf16(a1, b1, accB[1], 0, 0, 0);
            }
        }
        // elementwise -> decay/drive (fast softplus)
        const int scol = nt * 16 + lr;
        float dcy[8], u[8];
        {
            float bdv = bd[dep * 64 + scol];
            float bbv = bb[dep * 64 + scol];
            float eA  = __expf(A_log[dep * 64 + scol]);
            #pragma unroll
            for (int m = 0; m < 2; ++m)
                #pragma unroll
                for (int r = 0; r < 4; ++r) {
                    float dpre  = accD[m][r] + bdv;
                    float delta = (dpre > 20.f) ? dpre : __logf(1.f + __expf(dpre));
                    dcy[m * 4 + r] = __expf(-delta * eA);
                    u[m * 4 + r]   = delta * (accB[m][r] + bbv);
                }
        }
        // local (F,P) per 4-step chunk
        float F[2], P[2];
        #pragma unroll
        for (int m = 0; m < 2; ++m) {
            float h = 0.f, p = 1.f;
            #pragma unroll
            for (int r = 0; r < 4; ++r) { h = fmaf(dcy[m * 4 + r], h, u[m * 4 + r]); p *= dcy[m * 4 + r]; }
            F[m] = h; P[m] = p;
        }
        // intra-wave shuffle-fold over 8 chunks
        float hin_lo = 0.f, hin_hi = 0.f;
        if (mh == 0) {
            float hin = 0.f;
            #pragma unroll
            for (int j = 0; j < 8; ++j) {
                float Fj = __shfl(j < 4 ? F[0] : F[1], (j & 3) * 16 + lr, 64);
                float Pj = __shfl(j < 4 ? P[0] : P[1], (j & 3) * 16 + lr, 64);
                if (j == lg)     hin_lo = hin;
                if (j == 4 + lg) hin_hi = hin;
                hin = fmaf(Pj, hin, Fj);
            }
            if (lg == 0) scanF[scol] = hin;
        }
        __syncthreads();
        if (mh == 1) {
            float hin = scanF[scol];
            #pragma unroll
            for (int j = 0; j < 8; ++j) {
                float Fj = __shfl(j < 4 ? F[0] : F[1], (j & 3) * 16 + lr, 64);
                float Pj = __shfl(j < 4 ? P[0] : P[1], (j & 3) * 16 + lr, 64);
                if (j == lg)     hin_lo = hin;
                if (j == 4 + lg) hin_hi = hin;
                hin = fmaf(Pj, hin, Fj);
            }
        }
        // apply + write hs
        #pragma unroll
        for (int m = 0; m < 2; ++m) {
            float h = m ? hin_hi : hin_lo;
            #pragma unroll
            for (int r = 0; r < 4; ++r) {
                h = fmaf(dcy[m * 4 + r], h, u[m * 4 + r]);
                int t = 32 * mh + 16 * m + 4 * lg + r;
                *(unsigned short*)(sm + HS_B + hs_off(t, scol * 2)) = f2b(h);
            }
            if (m == 1 && mh == 1 && lg == 3) hT[scol] = h;
        }
        __syncthreads();   // hs + hT visible

        // ---- prefetch Wc fragments into registers (latency hides under stm matvec) ----
        bf16x8 wpre[2][4];
        {
            const unsigned short* WcA = pack + BC_OFF + (dep * 32 + w * 4) * 1024;
            #pragma unroll
            for (int ks = 0; ks < 2; ++ks)
                #pragma unroll
                for (int dt = 0; dt < 4; ++dt)
                    wpre[ks][dt] = *(const bf16x8*)(WcA + (dt * 2 + ks) * 512 + lane * 8);
        }

        // ================= shot-term: stm[d] = bs + hT @ Ws (bf16) =================
        {
            const unsigned short* WsP = pack + WS_OFF + dep * (NS * ND);
            float acc = bs[dep * ND + tid];
            #pragma unroll 8
            for (int s = 0; s < 64; ++s) acc = fmaf(hT[s], b2f(WsP[s * ND + tid]), acc);
            stm[tid] = acc;
        }
        __syncthreads();   // stm ready (barrier moved BEFORE phase C)

        // ======== fused phase C + epilogue: per tt, MFMA then store (no barrier between) ========
        {
            const float* bcd = bc + dep * ND;
            const float* Dpd = Dp + dep * ND;
            // hoisted per-dt constants
            f32x4 base[4], dp4[4];
            #pragma unroll
            for (int dt = 0; dt < 4; ++dt) {
                int d0 = w * 64 + dt * 16 + 4 * lg;
                f32x4 bc4 = *(const f32x4*)&bcd[d0];
                f32x4 st4 = *(const f32x4*)&stm[d0];
                base[dt] = bc4 + st4;
                dp4[dt]  = *(const f32x4*)&Dpd[d0];
            }
            f32x4 psumv[4] = {f32x4{0,0,0,0}, f32x4{0,0,0,0}, f32x4{0,0,0,0}, f32x4{0,0,0,0}};
            #pragma unroll
            for (int tt = 0; tt < 4; ++tt) {
                int t = tt * 16 + lr;
                bf16x8 hfr0 = *(const bf16x8*)(sm + HS_B + hs_off(t, lg * 16));
                bf16x8 hfr1 = *(const bf16x8*)(sm + HS_B + hs_off(t, 64 + lg * 16));
                f32x4 acc[4];
                #pragma unroll
                for (int dt = 0; dt < 4; ++dt) {
                    acc[dt] = __builtin_amdgcn_mfma_f32_16x16x32_bf16(wpre[0][dt], hfr0, f32x4{0,0,0,0}, 0, 0, 0);
                    acc[dt] = __builtin_amdgcn_mfma_f32_16x16x32_bf16(wpre[1][dt], hfr1, acc[dt], 0, 0, 0);
                }
                #pragma unroll
                for (int dt = 0; dt < 4; ++dt) {
                    int d0 = w * 64 + dt * 16 + 4 * lg;
                    ushort4 xq = *(const ushort4*)(sm + XH_B + xh_off(t, d0 * 2));
                    f32x4 v4;
                    v4.x = acc[dt].x + base[dt].x + b2f(xq.x) * dp4[dt].x;
                    v4.y = acc[dt].y + base[dt].y + b2f(xq.y) * dp4[dt].y;
                    v4.z = acc[dt].z + base[dt].z + b2f(xq.z) * dp4[dt].z;
                    v4.w = acc[dt].w + base[dt].w + b2f(xq.w) * dp4[dt].w;
                    if (dep == 0) {
                        ushort4 q;
                        q.x = f2b(v4.x); q.y = f2b(v4.y); q.z = f2b(v4.z); q.w = f2b(v4.w);
                        *(ushort4*)(sm + XH_B + xh_off(t, d0 * 2)) = q;
                    } else {
                        __builtin_nontemporal_store(v4, (f32x4*)&out_hidden[((size_t)b * NT + t) * ND + d0]);
                        psumv[dt] += v4;
                    }
                }
            }
            if (dep == 1) {
                // reduce over lr lanes (t coverage) within 16-lane groups
                #pragma unroll
                for (int dt = 0; dt < 4; ++dt)
                    #pragma unroll
                    for (int c = 0; c < 4; ++c) {
                        float v = psumv[dt][c];
                        v += __shfl_xor(v, 1, 64);
                        v += __shfl_xor(v, 2, 64);
                        v += __shfl_xor(v, 4, 64);
                        v += __shfl_xor(v, 8, 64);
                        psumv[dt][c] = v;
                    }
                if (lr == 0) {
                    // stm slice is wave-private; reads above were by this same wave (in-order)
                    #pragma unroll
                    for (int dt = 0; dt < 4; ++dt) {
                        int d0 = w * 64 + dt * 16 + 4 * lg;
                        #pragma unroll
                        for (int c = 0; c < 4; ++c)
                            stm[d0 + c] = psumv[dt][c] * (1.0f / 64.0f) + stm[d0 + c];
                    }
                }
            }
        }
        __syncthreads();
    } // depth

    // ================= LayerNorm on pooled (in stm) =================
    float pv = stm[tid];
    float s1 = pv, s2 = pv * pv;
    #pragma unroll
    for (int off = 32; off; off >>= 1) {
        s1 += __shfl_down(s1, off, 64);
        s2 += __shfl_down(s2, off, 64);
    }
    if (lane == 0) { red[w] = s1; red[8 + w] = s2; }
    __syncthreads();
    if (tid == 0) {
        float a = 0.f, q = 0.f;
        for (int i = 0; i < 8; ++i) { a += red[i]; q += red[8 + i]; }
        float mu = a * (1.0f / ND);
        float var = q * (1.0f / ND) - mu * mu;
        red[16] = mu;
        red[17] = rsqrtf(var + LN_EPS);
    }
    __syncthreads();
    out_shot[(size_t)b * ND + tid] = (pv - red[16]) * red[17] * gma[tid] + bta[tid];
}

extern "C" void kernel_launch(void* const* d_in, const int* in_sizes, int n_in,
                              void* d_out, int out_size, void* d_ws, size_t ws_size,
                              hipStream_t stream) {
    const float* tokens  = (const float*)d_in[0];
    const float* pos_emb = (const float*)d_in[1];
    const float* A_log   = (const float*)d_in[2];
    const float* Wd      = (const float*)d_in[3];
    const float* bd      = (const float*)d_in[4];
    const float* Wb      = (const float*)d_in[5];
    const float* bb      = (const float*)d_in[6];
    const float* Wc      = (const float*)d_in[7];
    const float* bc      = (const float*)d_in[8];
    const float* Dp      = (const float*)d_in[9];
    const float* Ws      = (const float*)d_in[10];
    const float* bs      = (const float*)d_in[11];
    const float* gma     = (const float*)d_in[12];
    const float* bta     = (const float*)d_in[13];

    unsigned short* pack = (unsigned short*)d_ws;   // 589824 B
    float* out_hidden = (float*)d_out;
    float* out_shot   = (float*)d_out + (size_t)NB * NT * ND;

    prep_pack<<<(PACK_ELEMS + 255) / 256, 256, 0, stream>>>(Wd, Wb, Wc, Ws, pos_emb, pack);

    (void)hipFuncSetAttribute((const void*)ssm_mfma,
                              hipFuncAttributeMaxDynamicSharedMemorySize,
                              (int)LDS_BYTES);
    ssm_mfma<<<NB, NTH, LDS_BYTES, stream>>>(
        tokens, A_log, bd, bb, bc, Dp, bs, gma, bta,
        pack, out_hidden, out_shot);
}

// Round 14
// 280.595 us; speedup vs baseline: 2.7774x; 2.7774x over previous
//
#include <hip/hip_runtime.h>
#include <hip/hip_bf16.h>
#include <math.h>

typedef __attribute__((ext_vector_type(8))) short bf16x8;
typedef __attribute__((ext_vector_type(4))) float f32x4;

#define NB 2048
#define NT 64
#define ND 512
#define NS 64
#define NTH 512
#define LN_EPS 1e-5f

// ---- LDS layout (bytes) ----
#define XH_B    0        // bf16 [64][512] swizzled (65536)
#define HS_B    65536    // bf16 [64][64] swizzled (8192)
#define SCANF_B 73728    // f32 [64]
#define HT_B    73984    // f32 [64]
#define STM_B   74240    // f32 [512]
#define RED_B   76288    // f32 [32]
#define LDS_BYTES 76416  // x2 = 152832 <= 160KiB -> 2 blocks/CU

// ws (ushort): BdPack [2][4][16][64][8] @0 ; BbPack @65536 ; WcPack [2][32][2][64][8] @131072 ;
//              WsP [2][64][512] @196608 ; posP [64][512] @262144
#define BB_OFF  65536
#define BC_OFF  131072
#define WS_OFF  196608
#define POS_OFF 262144
#define PACK_ELEMS 294912

__device__ __forceinline__ unsigned short f2b(float x) {
    __hip_bfloat16 h = __float2bfloat16(x);
    return *(unsigned short*)&h;
}
__device__ __forceinline__ float b2f(unsigned short u) {
    __hip_bfloat16 h; *(unsigned short*)&h = u;
    return __bfloat162float(h);
}
__device__ __forceinline__ int xh_off(int t, int cb) { return t * 1024 + (cb ^ ((t & 15) << 4)); }
__device__ __forceinline__ int hs_off(int t, int cb) { return t * 128  + (cb ^ ((t & 7)  << 4)); }

// ---------------- prep: pack weights + pos_emb to bf16 ----------------
__global__ void prep_pack(const float* __restrict__ Wd, const float* __restrict__ Wb,
                          const float* __restrict__ Wc, const float* __restrict__ Ws,
                          const float* __restrict__ pos_emb,
                          unsigned short* __restrict__ pack) {
    int i = blockIdx.x * 256 + threadIdx.x;
    if (i >= PACK_ELEMS) return;
    float v;
    if (i >= POS_OFF) {
        v = pos_emb[i - POS_OFF];
    } else {
        int which = i >> 16;          // 0=Bd 1=Bb 2=Wc 3=Ws
        int r = i & 0xFFFF;
        if (which < 2) {
            int j = r & 7, l = (r >> 3) & 63, ks = (r >> 9) & 15, nt = (r >> 13) & 3, dep = r >> 15;
            int s = nt * 16 + (l & 15);
            int k = ks * 32 + (l >> 4) * 8 + j;
            const float* W = which ? Wb : Wd;
            v = W[(dep * 512 + k) * 64 + s];
        } else if (which == 2) {
            int j = r & 7, l = (r >> 3) & 63, ks = (r >> 9) & 1, ntg = (r >> 10) & 31, dep = r >> 15;
            int d = ntg * 16 + (l & 15);
            int k = ks * 32 + (l >> 4) * 8 + j;
            v = Wc[(dep * 64 + k) * 512 + d];
        } else {
            int dep = r >> 15, rem = r & 0x7FFF;
            v = Ws[dep * (NS * ND) + rem];
        }
    }
    pack[i] = f2b(v);
}

// ---------------- main fused kernel: 1 block per batch element ----------------
__global__ __launch_bounds__(NTH, 4)
void ssm_mfma(const float* __restrict__ tokens,
              const float* __restrict__ A_log,
              const float* __restrict__ bd, const float* __restrict__ bb,
              const float* __restrict__ bc, const float* __restrict__ Dp,
              const float* __restrict__ bs,
              const float* __restrict__ gma, const float* __restrict__ bta,
              const unsigned short* __restrict__ pack,
              float* __restrict__ out_hidden, float* __restrict__ out_shot)
{
    extern __shared__ char sm[];
    float* scanF = (float*)(sm + SCANF_B);
    float* hT    = (float*)(sm + HT_B);
    float* stm   = (float*)(sm + STM_B);
    float* red   = (float*)(sm + RED_B);

    const int tid  = threadIdx.x;
    const int b    = blockIdx.x;
    const int lane = tid & 63;
    const int w    = tid >> 6;
    const int lr   = lane & 15;
    const int lg   = lane >> 4;
    const int nt   = w & 3;
    const int mh   = w >> 2;

    // ---- stage tokens + bf16 pos_emb -> bf16 swizzled xh ----
    {
        const f32x4*   tp = (const f32x4*)(tokens + (size_t)b * (NT * ND));
        const ushort4* pp = (const ushort4*)(pack + POS_OFF);
        #pragma unroll
        for (int i = 0; i < 16; ++i) {
            int f = i * NTH + tid;
            f32x4 a = __builtin_nontemporal_load(&tp[f]);
            ushort4 p = pp[f];
            int row = f >> 7, cb = (f & 127) * 8;
            ushort4 q;
            q.x = f2b(a.x + b2f(p.x));
            q.y = f2b(a.y + b2f(p.y));
            q.z = f2b(a.z + b2f(p.z));
            q.w = f2b(a.w + b2f(p.w));
            *(ushort4*)(sm + XH_B + xh_off(row, cb)) = q;
        }
    }
    __syncthreads();

    for (int dep = 0; dep < 2; ++dep) {
        // ================= phase A: delta_pre / drive_pre via MFMA =================
        f32x4 accD[2] = {f32x4{0,0,0,0}, f32x4{0,0,0,0}};
        f32x4 accB[2] = {f32x4{0,0,0,0}, f32x4{0,0,0,0}};
        {
            const unsigned short* BdP = pack + (dep * 4 + nt) * 8192;
            const unsigned short* BbP = BdP + BB_OFF;
            const int rowA0 = 32 * mh + lr;
            const int rowA1 = rowA0 + 16;
            #pragma unroll 4
            for (int ks = 0; ks < 16; ++ks) {
                int cb = ks * 64 + lg * 16;
                bf16x8 a0 = *(const bf16x8*)(sm + XH_B + xh_off(rowA0, cb));
                bf16x8 a1 = *(const bf16x8*)(sm + XH_B + xh_off(rowA1, cb));
                bf16x8 b0 = *(const bf16x8*)(BdP + ks * 512 + lane * 8);
                bf16x8 b1 = *(const bf16x8*)(BbP + ks * 512 + lane * 8);
                accD[0] = __builtin_amdgcn_mfma_f32_16x16x32_bf16(a0, b0, accD[0], 0, 0, 0);
                accD[1] = __builtin_amdgcn_mfma_f32_16x16x32_bf16(a1, b0, accD[1], 0, 0, 0);
                accB[0] = __builtin_amdgcn_mfma_f32_16x16x32_bf16(a0, b1, accB[0], 0, 0, 0);
                accB[1] = __builtin_amdgcn_mfma_f32_16x16x32_bf16(a1, b1, accB[1], 0, 0, 0);
            }
        }
        // elementwise -> decay/drive (fast softplus)
        const int scol = nt * 16 + lr;
        float dcy[8], u[8];
        {
            float bdv = bd[dep * 64 + scol];
            float bbv = bb[dep * 64 + scol];
            float eA  = __expf(A_log[dep * 64 + scol]);
            #pragma unroll
            for (int m = 0; m < 2; ++m)
                #pragma unroll
                for (int r = 0; r < 4; ++r) {
                    float dpre  = accD[m][r] + bdv;
                    float delta = (dpre > 20.f) ? dpre : __logf(1.f + __expf(dpre));
                    dcy[m * 4 + r] = __expf(-delta * eA);
                    u[m * 4 + r]   = delta * (accB[m][r] + bbv);
                }
        }
        // local (F,P) per 4-step chunk
        float F[2], P[2];
        #pragma unroll
        for (int m = 0; m < 2; ++m) {
            float h = 0.f, p = 1.f;
            #pragma unroll
            for (int r = 0; r < 4; ++r) { h = fmaf(dcy[m * 4 + r], h, u[m * 4 + r]); p *= dcy[m * 4 + r]; }
            F[m] = h; P[m] = p;
        }
        // intra-wave shuffle-fold over 8 chunks
        float hin_lo = 0.f, hin_hi = 0.f;
        if (mh == 0) {
            float hin = 0.f;
            #pragma unroll
            for (int j = 0; j < 8; ++j) {
                float Fj = __shfl(j < 4 ? F[0] : F[1], (j & 3) * 16 + lr, 64);
                float Pj = __shfl(j < 4 ? P[0] : P[1], (j & 3) * 16 + lr, 64);
                if (j == lg)     hin_lo = hin;
                if (j == 4 + lg) hin_hi = hin;
                hin = fmaf(Pj, hin, Fj);
            }
            if (lg == 0) scanF[scol] = hin;
        }
        __syncthreads();
        if (mh == 1) {
            float hin = scanF[scol];
            #pragma unroll
            for (int j = 0; j < 8; ++j) {
                float Fj = __shfl(j < 4 ? F[0] : F[1], (j & 3) * 16 + lr, 64);
                float Pj = __shfl(j < 4 ? P[0] : P[1], (j & 3) * 16 + lr, 64);
                if (j == lg)     hin_lo = hin;
                if (j == 4 + lg) hin_hi = hin;
                hin = fmaf(Pj, hin, Fj);
            }
        }
        // apply + write hs
        #pragma unroll
        for (int m = 0; m < 2; ++m) {
            float h = m ? hin_hi : hin_lo;
            #pragma unroll
            for (int r = 0; r < 4; ++r) {
                h = fmaf(dcy[m * 4 + r], h, u[m * 4 + r]);
                int t = 32 * mh + 16 * m + 4 * lg + r;
                *(unsigned short*)(sm + HS_B + hs_off(t, scol * 2)) = f2b(h);
            }
            if (m == 1 && mh == 1 && lg == 3) hT[scol] = h;
        }
        __syncthreads();

        // ---- prefetch Wc fragments into registers; latency hides under the stm matvec ----
        bf16x8 wpre[2][4];
        {
            const unsigned short* WcA = pack + BC_OFF + (dep * 32 + w * 4) * 1024;
            #pragma unroll
            for (int ks = 0; ks < 2; ++ks)
                #pragma unroll
                for (int dt = 0; dt < 4; ++dt)
                    wpre[ks][dt] = *(const bf16x8*)(WcA + (dt * 2 + ks) * 512 + lane * 8);
        }

        // ================= shot-term: stm[d] = bs + hT @ Ws (bf16) =================
        {
            const unsigned short* WsP = pack + WS_OFF + dep * (NS * ND);
            float acc = bs[dep * ND + tid];
            #pragma unroll 8
            for (int s = 0; s < 64; ++s) acc = fmaf(hT[s], b2f(WsP[s * ND + tid]), acc);
            stm[tid] = acc;
        }

        // ================= phase C (swapped): D[d][t] = Wc^T-frag x hs-frag =================
        // thread holds: t = tt*16+lr, d = w*64+dt*16+4*lg+r (r=0..3 consecutive)
        f32x4 accC[4][4];   // [tt][dt]
        #pragma unroll
        for (int tt = 0; tt < 4; ++tt)
            #pragma unroll
            for (int dt = 0; dt < 4; ++dt) accC[tt][dt] = f32x4{0, 0, 0, 0};
        {
            #pragma unroll
            for (int ks = 0; ks < 2; ++ks) {
                bf16x8 hfr[4];
                #pragma unroll
                for (int tt = 0; tt < 4; ++tt)
                    hfr[tt] = *(const bf16x8*)(sm + HS_B + hs_off(tt * 16 + lr, ks * 64 + lg * 16));
                #pragma unroll
                for (int dt = 0; dt < 4; ++dt) {
                    #pragma unroll
                    for (int tt = 0; tt < 4; ++tt)
                        accC[tt][dt] = __builtin_amdgcn_mfma_f32_16x16x32_bf16(wpre[ks][dt], hfr[tt], accC[tt][dt], 0, 0, 0);
                }
            }
        }
        __syncthreads();   // stm ready; hs reads done

        // ================= epilogue (r11-verbatim) =================
        {
            const float* bcd = bc + dep * ND;
            const float* Dpd = Dp + dep * ND;
            f32x4 psumv[4] = {f32x4{0,0,0,0}, f32x4{0,0,0,0}, f32x4{0,0,0,0}, f32x4{0,0,0,0}};
            #pragma unroll
            for (int tt = 0; tt < 4; ++tt) {
                int t = tt * 16 + lr;
                #pragma unroll
                for (int dt = 0; dt < 4; ++dt) {
                    int d0 = w * 64 + dt * 16 + 4 * lg;
                    ushort4 xq = *(const ushort4*)(sm + XH_B + xh_off(t, d0 * 2));
                    f32x4 bc4 = *(const f32x4*)&bcd[d0];
                    f32x4 dp4 = *(const f32x4*)&Dpd[d0];
                    f32x4 st4 = *(const f32x4*)&stm[d0];
                    f32x4 v4;
                    v4.x = accC[tt][dt].x + bc4.x + b2f(xq.x) * dp4.x + st4.x;
                    v4.y = accC[tt][dt].y + bc4.y + b2f(xq.y) * dp4.y + st4.y;
                    v4.z = accC[tt][dt].z + bc4.z + b2f(xq.z) * dp4.z + st4.z;
                    v4.w = accC[tt][dt].w + bc4.w + b2f(xq.w) * dp4.w + st4.w;
                    if (dep == 0) {
                        ushort4 q;
                        q.x = f2b(v4.x); q.y = f2b(v4.y); q.z = f2b(v4.z); q.w = f2b(v4.w);
                        *(ushort4*)(sm + XH_B + xh_off(t, d0 * 2)) = q;
                    } else {
                        __builtin_nontemporal_store(v4, (f32x4*)&out_hidden[((size_t)b * NT + t) * ND + d0]);
                        psumv[dt] += v4;
                    }
                }
            }
            if (dep == 1) {
                // reduce over lr lanes (t coverage) within 16-lane groups
                #pragma unroll
                for (int dt = 0; dt < 4; ++dt)
                    #pragma unroll
                    for (int c = 0; c < 4; ++c) {
                        float v = psumv[dt][c];
                        v += __shfl_xor(v, 1, 64);
                        v += __shfl_xor(v, 2, 64);
                        v += __shfl_xor(v, 4, 64);
                        v += __shfl_xor(v, 8, 64);
                        psumv[dt][c] = v;
                    }
                if (lr == 0) {
                    #pragma unroll
                    for (int dt = 0; dt < 4; ++dt) {
                        int d0 = w * 64 + dt * 16 + 4 * lg;
                        f32x4 st4 = *(const f32x4*)&stm[d0];
                        f32x4 nv = psumv[dt] * (1.0f / 64.0f) + st4;
                        *(f32x4*)&stm[d0] = nv;
                    }
                }
            }
        }
        __syncthreads();
    } // depth

    // ================= LayerNorm on pooled (in stm) =================
    float pv = stm[tid];
    float s1 = pv, s2 = pv * pv;
    #pragma unroll
    for (int off = 32; off; off >>= 1) {
        s1 += __shfl_down(s1, off, 64);
        s2 += __shfl_down(s2, off, 64);
    }
    if (lane == 0) { red[w] = s1; red[8 + w] = s2; }
    __syncthreads();
    if (tid == 0) {
        float a = 0.f, q = 0.f;
        for (int i = 0; i < 8; ++i) { a += red[i]; q += red[8 + i]; }
        float mu = a * (1.0f / ND);
        float var = q * (1.0f / ND) - mu * mu;
        red[16] = mu;
        red[17] = rsqrtf(var + LN_EPS);
    }
    __syncthreads();
    out_shot[(size_t)b * ND + tid] = (pv - red[16]) * red[17] * gma[tid] + bta[tid];
}

extern "C" void kernel_launch(void* const* d_in, const int* in_sizes, int n_in,
                              void* d_out, int out_size, void* d_ws, size_t ws_size,
                              hipStream_t stream) {
    const float* tokens  = (const float*)d_in[0];
    const float* pos_emb = (const float*)d_in[1];
    const float* A_log   = (const float*)d_in[2];
    const float* Wd      = (const float*)d_in[3];
    const float* bd      = (const float*)d_in[4];
    const float* Wb      = (const float*)d_in[5];
    const float* bb      = (const float*)d_in[6];
    const float* Wc      = (const float*)d_in[7];
    const float* bc      = (const float*)d_in[8];
    const float* Dp      = (const float*)d_in[9];
    const float* Ws      = (const float*)d_in[10];
    const float* bs      = (const float*)d_in[11];
    const float* gma     = (const float*)d_in[12];
    const float* bta     = (const float*)d_in[13];

    unsigned short* pack = (unsigned short*)d_ws;   // 589824 B
    float* out_hidden = (float*)d_out;
    float* out_shot   = (float*)d_out + (size_t)NB * NT * ND;

    prep_pack<<<(PACK_ELEMS + 255) / 256, 256, 0, stream>>>(Wd, Wb, Wc, Ws, pos_emb, pack);

    (void)hipFuncSetAttribute((const void*)ssm_mfma,
                              hipFuncAttributeMaxDynamicSharedMemorySize,
                              (int)LDS_BYTES);
    ssm_mfma<<<NB, NTH, LDS_BYTES, stream>>>(
        tokens, A_log, bd, bb, bc, Dp, bs, gma, bta,
        pack, out_hidden, out_shot);
}

// Round 15
// 255.512 us; speedup vs baseline: 3.0501x; 1.0982x over previous
//
#include <hip/hip_runtime.h>
#include <hip/hip_bf16.h>
#include <math.h>

typedef __attribute__((ext_vector_type(8))) short bf16x8;
typedef __attribute__((ext_vector_type(4))) float f32x4;

#define NB 2048
#define NT 64
#define ND 512
#define NS 64
#define NTH 512
#define LN_EPS 1e-5f

// ---- LDS layout (bytes) ----
#define XH_B    0        // bf16 [64][512] swizzled (65536)
#define HS_B    65536    // bf16 [64][64] swizzled (8192)
#define SCANF_B 73728    // f32 [64]
#define HT_B    73984    // f32 [64]
#define STM_B   74240    // f32 [512]
#define RED_B   76288    // f32 [32]
#define LDS_BYTES 76416  // x2 = 152832 <= 160KiB -> 2 blocks/CU

// ws (ushort): BdPack [2][4][16][64][8] @0 ; BbPack @65536 ; WcPack [2][32][2][64][8] @131072 ;
//              WsP [2][64][512] @196608 ; posP [64][512] @262144
#define BB_OFF  65536
#define BC_OFF  131072
#define WS_OFF  196608
#define POS_OFF 262144
#define PACK_ELEMS 294912

__device__ __forceinline__ unsigned short f2b(float x) {
    __hip_bfloat16 h = __float2bfloat16(x);
    return *(unsigned short*)&h;
}
__device__ __forceinline__ float b2f(unsigned short u) {
    __hip_bfloat16 h; *(unsigned short*)&h = u;
    return __bfloat162float(h);
}
__device__ __forceinline__ int xh_off(int t, int cb) { return t * 1024 + (cb ^ ((t & 15) << 4)); }
__device__ __forceinline__ int hs_off(int t, int cb) { return t * 128  + (cb ^ ((t & 7)  << 4)); }

// ---------------- prep: pack weights + pos_emb to bf16 ----------------
__global__ void prep_pack(const float* __restrict__ Wd, const float* __restrict__ Wb,
                          const float* __restrict__ Wc, const float* __restrict__ Ws,
                          const float* __restrict__ pos_emb,
                          unsigned short* __restrict__ pack) {
    int i = blockIdx.x * 256 + threadIdx.x;
    if (i >= PACK_ELEMS) return;
    float v;
    if (i >= POS_OFF) {
        v = pos_emb[i - POS_OFF];
    } else {
        int which = i >> 16;          // 0=Bd 1=Bb 2=Wc 3=Ws
        int r = i & 0xFFFF;
        if (which < 2) {
            int j = r & 7, l = (r >> 3) & 63, ks = (r >> 9) & 15, nt = (r >> 13) & 3, dep = r >> 15;
            int s = nt * 16 + (l & 15);
            int k = ks * 32 + (l >> 4) * 8 + j;
            const float* W = which ? Wb : Wd;
            v = W[(dep * 512 + k) * 64 + s];
        } else if (which == 2) {
            int j = r & 7, l = (r >> 3) & 63, ks = (r >> 9) & 1, ntg = (r >> 10) & 31, dep = r >> 15;
            int d = ntg * 16 + (l & 15);
            int k = ks * 32 + (l >> 4) * 8 + j;
            v = Wc[(dep * 64 + k) * 512 + d];
        } else {
            int dep = r >> 15, rem = r & 0x7FFF;
            v = Ws[dep * (NS * ND) + rem];
        }
    }
    pack[i] = f2b(v);
}

// ---------------- main fused kernel: 1 block per batch element ----------------
__global__ __launch_bounds__(NTH, 4)
void ssm_mfma(const float* __restrict__ tokens,
              const float* __restrict__ A_log,
              const float* __restrict__ bd, const float* __restrict__ bb,
              const float* __restrict__ bc, const float* __restrict__ Dp,
              const float* __restrict__ bs,
              const float* __restrict__ gma, const float* __restrict__ bta,
              const unsigned short* __restrict__ pack,
              float* __restrict__ out_hidden, float* __restrict__ out_shot)
{
    extern __shared__ char sm[];
    float* scanF = (float*)(sm + SCANF_B);
    float* hT    = (float*)(sm + HT_B);
    float* stm   = (float*)(sm + STM_B);
    float* red   = (float*)(sm + RED_B);

    const int tid  = threadIdx.x;
    const int b    = blockIdx.x;
    const int lane = tid & 63;
    const int w    = tid >> 6;
    const int lr   = lane & 15;
    const int lg   = lane >> 4;
    const int nt   = w & 3;
    const int mh   = w >> 2;

    // ---- stage tokens + bf16 pos_emb -> bf16 swizzled xh ----
    {
        const f32x4*   tp = (const f32x4*)(tokens + (size_t)b * (NT * ND));
        const ushort4* pp = (const ushort4*)(pack + POS_OFF);
        #pragma unroll
        for (int i = 0; i < 16; ++i) {
            int f = i * NTH + tid;
            f32x4 a = __builtin_nontemporal_load(&tp[f]);
            ushort4 p = pp[f];
            int row = f >> 7, cb = (f & 127) * 8;
            ushort4 q;
            q.x = f2b(a.x + b2f(p.x));
            q.y = f2b(a.y + b2f(p.y));
            q.z = f2b(a.z + b2f(p.z));
            q.w = f2b(a.w + b2f(p.w));
            *(ushort4*)(sm + XH_B + xh_off(row, cb)) = q;
        }
    }
    __syncthreads();

    for (int dep = 0; dep < 2; ++dep) {
        // ================= phase A: delta_pre / drive_pre via MFMA =================
        f32x4 accD[2] = {f32x4{0,0,0,0}, f32x4{0,0,0,0}};
        f32x4 accB[2] = {f32x4{0,0,0,0}, f32x4{0,0,0,0}};
        {
            const unsigned short* BdP = pack + (dep * 4 + nt) * 8192;
            const unsigned short* BbP = BdP + BB_OFF;
            const int rowA0 = 32 * mh + lr;
            const int rowA1 = rowA0 + 16;
            #pragma unroll 4
            for (int ks = 0; ks < 16; ++ks) {
                int cb = ks * 64 + lg * 16;
                bf16x8 a0 = *(const bf16x8*)(sm + XH_B + xh_off(rowA0, cb));
                bf16x8 a1 = *(const bf16x8*)(sm + XH_B + xh_off(rowA1, cb));
                bf16x8 b0 = *(const bf16x8*)(BdP + ks * 512 + lane * 8);
                bf16x8 b1 = *(const bf16x8*)(BbP + ks * 512 + lane * 8);
                accD[0] = __builtin_amdgcn_mfma_f32_16x16x32_bf16(a0, b0, accD[0], 0, 0, 0);
                accD[1] = __builtin_amdgcn_mfma_f32_16x16x32_bf16(a1, b0, accD[1], 0, 0, 0);
                accB[0] = __builtin_amdgcn_mfma_f32_16x16x32_bf16(a0, b1, accB[0], 0, 0, 0);
                accB[1] = __builtin_amdgcn_mfma_f32_16x16x32_bf16(a1, b1, accB[1], 0, 0, 0);
            }
        }
        // elementwise -> decay/drive (fast softplus)
        const int scol = nt * 16 + lr;
        float dcy[8], u[8];
        {
            float bdv = bd[dep * 64 + scol];
            float bbv = bb[dep * 64 + scol];
            float eA  = __expf(A_log[dep * 64 + scol]);
            #pragma unroll
            for (int m = 0; m < 2; ++m)
                #pragma unroll
                for (int r = 0; r < 4; ++r) {
                    float dpre  = accD[m][r] + bdv;
                    float delta = (dpre > 20.f) ? dpre : __logf(1.f + __expf(dpre));
                    dcy[m * 4 + r] = __expf(-delta * eA);
                    u[m * 4 + r]   = delta * (accB[m][r] + bbv);
                }
        }
        // local (F,P) per 4-step chunk
        float F[2], P[2];
        #pragma unroll
        for (int m = 0; m < 2; ++m) {
            float h = 0.f, p = 1.f;
            #pragma unroll
            for (int r = 0; r < 4; ++r) { h = fmaf(dcy[m * 4 + r], h, u[m * 4 + r]); p *= dcy[m * 4 + r]; }
            F[m] = h; P[m] = p;
        }
        // intra-wave shuffle-fold over 8 chunks
        float hin_lo = 0.f, hin_hi = 0.f;
        if (mh == 0) {
            float hin = 0.f;
            #pragma unroll
            for (int j = 0; j < 8; ++j) {
                float Fj = __shfl(j < 4 ? F[0] : F[1], (j & 3) * 16 + lr, 64);
                float Pj = __shfl(j < 4 ? P[0] : P[1], (j & 3) * 16 + lr, 64);
                if (j == lg)     hin_lo = hin;
                if (j == 4 + lg) hin_hi = hin;
                hin = fmaf(Pj, hin, Fj);
            }
            if (lg == 0) scanF[scol] = hin;
        }
        __syncthreads();
        if (mh == 1) {
            float hin = scanF[scol];
            #pragma unroll
            for (int j = 0; j < 8; ++j) {
                float Fj = __shfl(j < 4 ? F[0] : F[1], (j & 3) * 16 + lr, 64);
                float Pj = __shfl(j < 4 ? P[0] : P[1], (j & 3) * 16 + lr, 64);
                if (j == lg)     hin_lo = hin;
                if (j == 4 + lg) hin_hi = hin;
                hin = fmaf(Pj, hin, Fj);
            }
        }
        // apply + write hs
        #pragma unroll
        for (int m = 0; m < 2; ++m) {
            float h = m ? hin_hi : hin_lo;
            #pragma unroll
            for (int r = 0; r < 4; ++r) {
                h = fmaf(dcy[m * 4 + r], h, u[m * 4 + r]);
                int t = 32 * mh + 16 * m + 4 * lg + r;
                *(unsigned short*)(sm + HS_B + hs_off(t, scol * 2)) = f2b(h);
            }
            if (m == 1 && mh == 1 && lg == 3) hT[scol] = h;
        }
        __syncthreads();

        // ================= shot-term: stm[d] = bs + hT @ Ws (bf16) =================
        {
            const unsigned short* WsP = pack + WS_OFF + dep * (NS * ND);
            float acc = bs[dep * ND + tid];
            #pragma unroll 8
            for (int s = 0; s < 64; ++s) acc = fmaf(hT[s], b2f(WsP[s * ND + tid]), acc);
            stm[tid] = acc;
        }

        // ================= phase C (swapped): D[d][t] = Wc^T-frag x hs-frag =================
        // thread holds: t = tt*16+lr, d = w*64+dt*16+4*lg+r (r=0..3 consecutive)
        f32x4 accC[4][4];   // [tt][dt]
        #pragma unroll
        for (int tt = 0; tt < 4; ++tt)
            #pragma unroll
            for (int dt = 0; dt < 4; ++dt) accC[tt][dt] = f32x4{0, 0, 0, 0};
        {
            const unsigned short* WcA = pack + BC_OFF + (dep * 32 + w * 4) * 1024;
            #pragma unroll
            for (int ks = 0; ks < 2; ++ks) {
                bf16x8 hfr[4];
                #pragma unroll
                for (int tt = 0; tt < 4; ++tt)
                    hfr[tt] = *(const bf16x8*)(sm + HS_B + hs_off(tt * 16 + lr, ks * 64 + lg * 16));
                #pragma unroll
                for (int dt = 0; dt < 4; ++dt) {
                    bf16x8 wfr = *(const bf16x8*)(WcA + (dt * 2 + ks) * 512 + lane * 8);
                    #pragma unroll
                    for (int tt = 0; tt < 4; ++tt)
                        accC[tt][dt] = __builtin_amdgcn_mfma_f32_16x16x32_bf16(wfr, hfr[tt], accC[tt][dt], 0, 0, 0);
                }
            }
        }
        __syncthreads();   // stm ready; hs reads done

        // ================= epilogue (r5-verbatim) =================
        {
            const float* bcd = bc + dep * ND;
            const float* Dpd = Dp + dep * ND;
            f32x4 psumv[4] = {f32x4{0,0,0,0}, f32x4{0,0,0,0}, f32x4{0,0,0,0}, f32x4{0,0,0,0}};
            #pragma unroll
            for (int tt = 0; tt < 4; ++tt) {
                int t = tt * 16 + lr;
                #pragma unroll
                for (int dt = 0; dt < 4; ++dt) {
                    int d0 = w * 64 + dt * 16 + 4 * lg;
                    ushort4 xq = *(const ushort4*)(sm + XH_B + xh_off(t, d0 * 2));
                    f32x4 bc4 = *(const f32x4*)&bcd[d0];
                    f32x4 dp4 = *(const f32x4*)&Dpd[d0];
                    f32x4 st4 = *(const f32x4*)&stm[d0];
                    f32x4 v4;
                    v4.x = accC[tt][dt].x + bc4.x + b2f(xq.x) * dp4.x + st4.x;
                    v4.y = accC[tt][dt].y + bc4.y + b2f(xq.y) * dp4.y + st4.y;
                    v4.z = accC[tt][dt].z + bc4.z + b2f(xq.z) * dp4.z + st4.z;
                    v4.w = accC[tt][dt].w + bc4.w + b2f(xq.w) * dp4.w + st4.w;
                    if (dep == 0) {
                        ushort4 q;
                        q.x = f2b(v4.x); q.y = f2b(v4.y); q.z = f2b(v4.z); q.w = f2b(v4.w);
                        *(ushort4*)(sm + XH_B + xh_off(t, d0 * 2)) = q;
                    } else {
                        __builtin_nontemporal_store(v4, (f32x4*)&out_hidden[((size_t)b * NT + t) * ND + d0]);
                        psumv[dt] += v4;
                    }
                }
            }
            if (dep == 1) {
                // reduce over lr lanes (t coverage) within 16-lane groups
                #pragma unroll
                for (int dt = 0; dt < 4; ++dt)
                    #pragma unroll
                    for (int c = 0; c < 4; ++c) {
                        float v = psumv[dt][c];
                        v += __shfl_xor(v, 1, 64);
                        v += __shfl_xor(v, 2, 64);
                        v += __shfl_xor(v, 4, 64);
                        v += __shfl_xor(v, 8, 64);
                        psumv[dt][c] = v;
                    }
                if (lr == 0) {
                    #pragma unroll
                    for (int dt = 0; dt < 4; ++dt) {
                        int d0 = w * 64 + dt * 16 + 4 * lg;
                        f32x4 st4 = *(const f32x4*)&stm[d0];
                        f32x4 nv = psumv[dt] * (1.0f / 64.0f) + st4;
                        *(f32x4*)&stm[d0] = nv;
                    }
                }
            }
        }
        __syncthreads();
    } // depth

    // ================= LayerNorm on pooled (in stm) =================
    float pv = stm[tid];
    float s1 = pv, s2 = pv * pv;
    #pragma unroll
    for (int off = 32; off; off >>= 1) {
        s1 += __shfl_down(s1, off, 64);
        s2 += __shfl_down(s2, off, 64);
    }
    if (lane == 0) { red[w] = s1; red[8 + w] = s2; }
    __syncthreads();
    if (tid == 0) {
        float a = 0.f, q = 0.f;
        for (int i = 0; i < 8; ++i) { a += red[i]; q += red[8 + i]; }
        float mu = a * (1.0f / ND);
        float var = q * (1.0f / ND) - mu * mu;
        red[16] = mu;
        red[17] = rsqrtf(var + LN_EPS);
    }
    __syncthreads();
    out_shot[(size_t)b * ND + tid] = (pv - red[16]) * red[17] * gma[tid] + bta[tid];
}

extern "C" void kernel_launch(void* const* d_in, const int* in_sizes, int n_in,
                              void* d_out, int out_size, void* d_ws, size_t ws_size,
                              hipStream_t stream) {
    const float* tokens  = (const float*)d_in[0];
    const float* pos_emb = (const float*)d_in[1];
    const float* A_log   = (const float*)d_in[2];
    const float* Wd      = (const float*)d_in[3];
    const float* bd      = (const float*)d_in[4];
    const float* Wb      = (const float*)d_in[5];
    const float* bb      = (const float*)d_in[6];
    const float* Wc      = (const float*)d_in[7];
    const float* bc      = (const float*)d_in[8];
    const float* Dp      = (const float*)d_in[9];
    const float* Ws      = (const float*)d_in[10];
    const float* bs      = (const float*)d_in[11];
    const float* gma     = (const float*)d_in[12];
    const float* bta     = (const float*)d_in[13];

    unsigned short* pack = (unsigned short*)d_ws;   // 589824 B
    float* out_hidden = (float*)d_out;
    float* out_shot   = (float*)d_out + (size_t)NB * NT * ND;

    prep_pack<<<(PACK_ELEMS + 255) / 256, 256, 0, stream>>>(Wd, Wb, Wc, Ws, pos_emb, pack);

    (void)hipFuncSetAttribute((const void*)ssm_mfma,
                              hipFuncAttributeMaxDynamicSharedMemorySize,
                              (int)LDS_BYTES);
    ssm_mfma<<<NB, NTH, LDS_BYTES, stream>>>(
        tokens, A_log, bd, bb, bc, Dp, bs, gma, bta,
        pack, out_hidden, out_shot);
}